// Round 12
// baseline (99.620 us; speedup 1.0000x reference)
//
#include <hip/hip_runtime.h>
#include <math.h>

#define SEARCH 7
#define PAD 3
#define S2 49
#define KNN 7
#define NCLASSES 20
#define H 64
#define W 2048
#define NPTS 131072
#define NTILES 32
#define TROWS 70                 /* rows -3..66 (zero-padded) */
#define TCOLS 70                 /* cols -3..66 (circular)    */
#define SPT 32                   /* sub-blocks per tile */
#define SLICE (NPTS / SPT)       /* 4096 points scanned per block */
#define KBLOCK 256
#define PPB 128                  /* points per pair-iteration */
#define QCAP 512
#define REPS 3                   /* DIAGNOSTIC: body repeated; idempotent */

// f64-packed key: bits = (1<<62) | (distbits<<6) | j ; positive normal doubles,
// value order == bit order == exact lex-(dist, j) order (R9-proven).
#define SENTINEL_BITS 0x7FE0000000000000ull
#define CUTOFF_KEYMAX 0x4000000FE000003Full   /* (1<<62)|(0x3f800000<<6)|63 */

struct InvG { float v[S2]; };

// min/max bubble insert into sorted doubles s0..s6 (13 f64 ops, keys unique)
#define INSF(KEY) do {                                                  \
    double _x = (KEY);                                                  \
    double _t;                                                          \
    _t = fmin(s0, _x); _x = fmax(s0, _x); s0 = _t;                      \
    _t = fmin(s1, _x); _x = fmax(s1, _x); s1 = _t;                      \
    _t = fmin(s2, _x); _x = fmax(s2, _x); s2 = _t;                      \
    _t = fmin(s3, _x); _x = fmax(s3, _x); s3 = _t;                      \
    _t = fmin(s4, _x); _x = fmax(s4, _x); s4 = _t;                      \
    _t = fmin(s5, _x); _x = fmax(s5, _x); s5 = _t;                      \
    s6 = fmin(s6, _x);                                                  \
} while (0)

#define CAND(J, RB, DX) do {                                            \
    float nb = ftile[(RB) + (DX)];                                      \
    nb = (nb < 0.0f) ? __builtin_inff() : nb;                           \
    float d = fabsf(nb - u) * invg.v[J];                                \
    unsigned long long kb = (1ull << 62)                                \
        | ((unsigned long long)__float_as_uint(d) << 6)                 \
        | (unsigned)(J);                                                \
    INSF(__longlong_as_double((long long)kb));                          \
} while (0)

__global__ __launch_bounds__(KBLOCK, 4) void knn_kernel(
    const float* __restrict__ proj_range,
    const float* __restrict__ unproj_range,
    const int* __restrict__ proj_argmax,
    const int* __restrict__ pxv,
    const int* __restrict__ pyv,
    int* __restrict__ outv,
    InvG invg)
{
    __shared__ float         ftile[TROWS * TCOLS];
    __shared__ unsigned char atile[TROWS * TCOLS];
    __shared__ double        kbuf[PPB][KNN];
    __shared__ unsigned queue[QCAP];
    __shared__ int qcnt;

    const int tid  = threadIdx.x;
    const int t    = blockIdx.x >> 5;        // tile
    const int sub  = blockIdx.x & 31;        // slice
    const int tbase = t << 6;
    const int lane = tid & 63;
    const int wave = tid >> 6;               // 0..3

#pragma unroll 1
    for (int rep = 0; rep < REPS; ++rep) {
        __syncthreads();                      // previous rep fully done
        if (tid == 0) qcnt = 0;

        // stage 70x70 padded tiles (R4/R7-proven; u8 classes)
#pragma unroll
        for (int it = 0; it < 18; ++it) {
            int r = it * 4 + wave;
            if (r < TROWS) {
                int sr = r - 3;
                bool vr = (unsigned)sr < (unsigned)H;
                int gb = (vr ? sr : 0) * W;
                int ca = (tbase - 3 + lane) & (W - 1);
                float fv = proj_range[gb + ca];
                int   av = proj_argmax[gb + ca];
                ftile[r * TCOLS + lane] = vr ? fv : 0.0f;
                atile[r * TCOLS + lane] = (unsigned char)(vr ? av : 0);
                if (lane < TCOLS - 64) {
                    int cb = (tbase - 3 + 64 + lane) & (W - 1);
                    float fv2 = proj_range[gb + cb];
                    int   av2 = proj_argmax[gb + cb];
                    ftile[r * TCOLS + 64 + lane] = vr ? fv2 : 0.0f;
                    atile[r * TCOLS + 64 + lane] = (unsigned char)(vr ? av2 : 0);
                }
            }
        }
        __syncthreads();                      // tiles ready, qcnt=0 visible

        // scan own slice of px; enqueue matches (px>>6 == t)  (R8-proven)
        {
            const int4* px4 = (const int4*)pxv;
            int base4 = (sub * SLICE) >> 2;
#pragma unroll
            for (int k = 0; k < 4; ++k) {
                int idx4 = base4 + k * KBLOCK + tid;
                int4 v = px4[idx4];
                int i0x = idx4 * 4;
#pragma unroll
                for (int e = 0; e < 4; ++e) {
                    int x = (e == 0) ? v.x : (e == 1) ? v.y : (e == 2) ? v.z : v.w;
                    if ((x >> 6) == t) {
                        int i = i0x + e;
                        int y = pyv[i];
                        int pos = atomicAdd(&qcnt, 1);
                        if (pos < QCAP)
                            queue[pos] = (unsigned)i | ((unsigned)(x & 63) << 17)
                                                    | ((unsigned)y << 23);
                    }
                }
            }
        }
        __syncthreads();
        const int count = min(qcnt, QCAP);

        const int pairp = wave >> 1;         // 0..1
        const int role  = wave & 1;          // wave-uniform
        const int pidx  = pairp * 64 + lane; // 0..127

        for (int base = 0; base < count; base += PPB) {
            int slot = base + pidx;
            bool active = slot < count;
            bool anyact = __ballot(active) != 0;
            unsigned pk = 0u; int i = 0, xl = 0, y = 0;

            if (anyact) {
                pk = active ? queue[slot] : 0u;
                i  = (int)(pk & 0x1FFFFu);
                xl = (int)((pk >> 17) & 63u);
                y  = (int)((pk >> 23) & 63u);
                float u = unproj_range[i];

                double s0, s1, s2, s3, s4, s5, s6;
                s0 = s1 = s2 = s3 = s4 = s5 = s6 =
                    __longlong_as_double((long long)SENTINEL_BITS);

                if (role == 0) {
#pragma unroll
                    for (int dy = -3; dy <= 0; ++dy) {
                        int rb = (y + dy + 3) * TCOLS + xl + 3;
                        const int dxmax = (dy == 0) ? -1 : 3;
#pragma unroll
                        for (int dx = -3; dx <= dxmax; ++dx) {
                            const int j = (dy + 3) * 7 + (dx + 3);
                            CAND(j, rb, dx);
                        }
                    }
                } else {
                    INSF(__longlong_as_double((long long)((1ull << 62) | 24ull)));
#pragma unroll
                    for (int dy = 0; dy <= 3; ++dy) {
                        int rb = (y + dy + 3) * TCOLS + xl + 3;
                        const int dxmin = (dy == 0) ? 1 : -3;
#pragma unroll
                        for (int dx = dxmin; dx <= 3; ++dx) {
                            const int j = (dy + 3) * 7 + (dx + 3);
                            CAND(j, rb, dx);
                        }
                    }
                    kbuf[pidx][0] = s0; kbuf[pidx][1] = s1; kbuf[pidx][2] = s2;
                    kbuf[pidx][3] = s3; kbuf[pidx][4] = s4; kbuf[pidx][5] = s5;
                    kbuf[pidx][6] = s6;
                }
                if (role == 0) {
                    __syncthreads();
                    double m0 = fmin(s0, kbuf[pidx][6]);
                    double m1 = fmin(s1, kbuf[pidx][5]);
                    double m2 = fmin(s2, kbuf[pidx][4]);
                    double m3 = fmin(s3, kbuf[pidx][3]);
                    double m4 = fmin(s4, kbuf[pidx][2]);
                    double m5 = fmin(s5, kbuf[pidx][1]);
                    double m6 = fmin(s6, kbuf[pidx][0]);

                    const double cutmax = __longlong_as_double((long long)CUTOFF_KEYMAX);
                    int c0, c1, c2, c3, c4, c5, c6;
#define CLSK(MK, CK) do {                                                \
                    long long kb = __double_as_longlong(MK);             \
                    int j = (int)(kb & 63);                              \
                    bool sel = (MK) <= cutmax;                           \
                    int dy7 = (j * 37) >> 8;                             \
                    int cc = (int)atile[(y + dy7) * TCOLS + xl + (j - dy7 * 7)]; \
                    CK = sel ? cc : 0;                                   \
                } while (0)
                    CLSK(m0, c0); CLSK(m1, c1); CLSK(m2, c2); CLSK(m3, c3);
                    CLSK(m4, c4); CLSK(m5, c5); CLSK(m6, c6);
#undef CLSK

                    int n0 = 1, n1 = 1, n2 = 1, n3 = 1, n4 = 1, n5 = 1, n6 = 1;
#define PAIRV(A, B) do { bool e = (c##A == c##B); n##A += e ? 1 : 0; n##B += e ? 1 : 0; } while (0)
                    PAIRV(0,1); PAIRV(0,2); PAIRV(0,3); PAIRV(0,4); PAIRV(0,5); PAIRV(0,6);
                    PAIRV(1,2); PAIRV(1,3); PAIRV(1,4); PAIRV(1,5); PAIRV(1,6);
                    PAIRV(2,3); PAIRV(2,4); PAIRV(2,5); PAIRV(2,6);
                    PAIRV(3,4); PAIRV(3,5); PAIRV(3,6);
                    PAIRV(4,5); PAIRV(4,6);
                    PAIRV(5,6);
#undef PAIRV

                    int best = 0;
#define SCORE(K) do {                                                    \
                    bool valid = (unsigned)(c##K - 1) < (unsigned)(NCLASSES - 1);\
                    int sc = valid ? ((n##K << 5) | (31 - c##K)) : 0;    \
                    best = max(best, sc);                                \
                } while (0)
                    SCORE(0); SCORE(1); SCORE(2); SCORE(3); SCORE(4); SCORE(5); SCORE(6);
#undef SCORE
                    if (active) outv[i] = (best == 0) ? 1 : (31 - (best & 31));
                    __syncthreads();
                } else {
                    __syncthreads();
                    __syncthreads();
                }
            } else {
                __syncthreads();
                __syncthreads();
            }
        }
    }
}

extern "C" void kernel_launch(void* const* d_in, const int* in_sizes, int n_in,
                              void* d_out, int out_size, void* d_ws, size_t ws_size,
                              hipStream_t stream) {
    const float* proj_range   = (const float*)d_in[0];
    const float* unproj_range = (const float*)d_in[1];
    const int*   proj_argmax  = (const int*)d_in[2];
    const int*   px           = (const int*)d_in[3];
    const int*   py           = (const int*)d_in[4];
    int* out = (int*)d_out;

    // Emulate numpy float32 pipeline for the inverse-gaussian table.
    InvG invg;
    float g[S2];
    for (int yy = 0; yy < SEARCH; ++yy) {
        for (int xx = 0; xx < SEARCH; ++xx) {
            float fdx = (float)xx - 3.0f;
            float fdy = (float)yy - 3.0f;
            float s   = fdx * fdx + fdy * fdy;
            float arg = -s / 2.0f;
            float e   = (float)exp((double)arg);
            float gg  = e / 6.2831855f;
            g[yy * SEARCH + xx] = gg;
        }
    }
    float r[8];
    for (int tt = 0; tt < 8; ++tt) r[tt] = g[tt];
    int ii;
    for (ii = 8; ii + 8 <= 48; ii += 8)
        for (int tt = 0; tt < 8; ++tt) r[tt] += g[ii + tt];
    float ssum = ((r[0] + r[1]) + (r[2] + r[3])) + ((r[4] + r[5]) + (r[6] + r[7]));
    for (; ii < S2; ++ii) ssum += g[ii];
    for (int tt = 0; tt < S2; ++tt) invg.v[tt] = 1.0f - (g[tt] / ssum);

    knn_kernel<<<NTILES * SPT, KBLOCK, 0, stream>>>(
        proj_range, unproj_range, proj_argmax, px, py, out, invg);
}

// Round 13
// 21.030 us; speedup vs baseline: 4.7370x; 4.7370x over previous
//
#include <hip/hip_runtime.h>
#include <math.h>

#define SEARCH 7
#define PAD 3
#define S2 49
#define KNN 7
#define NCLASSES 20
#define H 64
#define W 2048
#define NPTS 131072
#define NTILES 32
#define TROWS 70                 /* rows -3..66 (zero-padded) */
#define TCOLS 70                 /* cols -3..66 (circular)    */
#define SPT 32                   /* sub-blocks per tile */
#define SLICE (NPTS / SPT)       /* 4096 points scanned per block */
#define KBLOCK 256
#define PPB 128                  /* points per pair-iteration */
#define QCAP 512

// f64-packed key: bits = (1<<62) | (distbits<<6) | j ; positive normal doubles,
// value order == bit order == exact lex-(dist, j) order (R9-proven).
#define SENTINEL_BITS 0x7FE0000000000000ull
#define CUTOFF_KEYMAX 0x4000000FE000003Full   /* (1<<62)|(0x3f800000<<6)|63 */

struct InvG { float v[S2]; };

// min/max bubble insert into sorted doubles s0..s6 (13 f64 ops, keys unique)
#define INSF(KEY) do {                                                  \
    double _x = (KEY);                                                  \
    double _t;                                                          \
    _t = fmin(s0, _x); _x = fmax(s0, _x); s0 = _t;                      \
    _t = fmin(s1, _x); _x = fmax(s1, _x); s1 = _t;                      \
    _t = fmin(s2, _x); _x = fmax(s2, _x); s2 = _t;                      \
    _t = fmin(s3, _x); _x = fmax(s3, _x); s3 = _t;                      \
    _t = fmin(s4, _x); _x = fmax(s4, _x); s4 = _t;                      \
    _t = fmin(s5, _x); _x = fmax(s5, _x); s5 = _t;                      \
    s6 = fmin(s6, _x);                                                  \
} while (0)

#define CAND(J, RB, DX) do {                                            \
    float nb = ftile[(RB) + (DX)];                                      \
    nb = (nb < 0.0f) ? __builtin_inff() : nb;                           \
    float d = fabsf(nb - u) * invg.v[J];                                \
    unsigned long long kb = (1ull << 62)                                \
        | ((unsigned long long)__float_as_uint(d) << 6)                 \
        | (unsigned)(J);                                                \
    INSF(__longlong_as_double((long long)kb));                          \
} while (0)

__global__ __launch_bounds__(KBLOCK, 4) void knn_kernel(
    const float* __restrict__ proj_range,
    const float* __restrict__ unproj_range,
    const int* __restrict__ proj_argmax,
    const int* __restrict__ pxv,
    const int* __restrict__ pyv,
    int* __restrict__ outv,
    InvG invg)
{
    __shared__ float  ftile[TROWS * TCOLS];
    __shared__ double kbuf[PPB][KNN];
    __shared__ unsigned queue[QCAP];
    __shared__ int qcnt;

    const int tid  = threadIdx.x;
    const int t    = blockIdx.x >> 5;        // tile
    const int sub  = blockIdx.x & 31;        // slice
    const int tbase = t << 6;
    const int lane = tid & 63;
    const int wave = tid >> 6;               // 0..3

    if (tid == 0) qcnt = 0;

    // stage 70x70 padded range tile only (classes gathered from L2 in epilogue)
#pragma unroll
    for (int it = 0; it < 18; ++it) {
        int r = it * 4 + wave;
        if (r < TROWS) {
            int sr = r - 3;
            bool vr = (unsigned)sr < (unsigned)H;
            int gb = (vr ? sr : 0) * W;
            int ca = (tbase - 3 + lane) & (W - 1);
            float fv = proj_range[gb + ca];
            ftile[r * TCOLS + lane] = vr ? fv : 0.0f;
            if (lane < TCOLS - 64) {
                int cb = (tbase - 3 + 64 + lane) & (W - 1);
                float fv2 = proj_range[gb + cb];
                ftile[r * TCOLS + 64 + lane] = vr ? fv2 : 0.0f;
            }
        }
    }
    __syncthreads();                          // tile ready, qcnt=0 visible

    // scan own slice of px; enqueue matches (px>>6 == t)  (R8/R9-proven)
    {
        const int4* px4 = (const int4*)pxv;
        int base4 = (sub * SLICE) >> 2;
#pragma unroll
        for (int k = 0; k < 4; ++k) {
            int idx4 = base4 + k * KBLOCK + tid;
            int4 v = px4[idx4];
            int i0x = idx4 * 4;
#pragma unroll
            for (int e = 0; e < 4; ++e) {
                int x = (e == 0) ? v.x : (e == 1) ? v.y : (e == 2) ? v.z : v.w;
                if ((x >> 6) == t) {
                    int i = i0x + e;
                    int y = pyv[i];
                    int pos = atomicAdd(&qcnt, 1);
                    if (pos < QCAP)
                        queue[pos] = (unsigned)i | ((unsigned)(x & 63) << 17)
                                                | ((unsigned)y << 23);
                }
            }
        }
    }
    __syncthreads();
    const int count = min(qcnt, QCAP);

    const int pairp = wave >> 1;             // 0..1
    const int role  = wave & 1;              // wave-uniform
    const int pidx  = pairp * 64 + lane;     // 0..127

    for (int base = 0; base < count; base += PPB) {
        int slot = base + pidx;
        bool active = slot < count;
        bool anyact = __ballot(active) != 0;  // same for partner waves
        unsigned pk = 0u; int i = 0, xl = 0, y = 0;

        if (anyact) {
            pk = active ? queue[slot] : 0u;
            i  = (int)(pk & 0x1FFFFu);
            xl = (int)((pk >> 17) & 63u);
            y  = (int)((pk >> 23) & 63u);
            float u = unproj_range[i];

            double s0, s1, s2, s3, s4, s5, s6;
            s0 = s1 = s2 = s3 = s4 = s5 = s6 =
                __longlong_as_double((long long)SENTINEL_BITS);

            if (role == 0) {
                // j = 0..23 : rows dy=-3..-1 full, dy=0 dx=-3..-1 (proven split)
#pragma unroll
                for (int dy = -3; dy <= 0; ++dy) {
                    int rb = (y + dy + 3) * TCOLS + xl + 3;
                    const int dxmax = (dy == 0) ? -1 : 3;
#pragma unroll
                    for (int dx = -3; dx <= dxmax; ++dx) {
                        const int j = (dy + 3) * 7 + (dx + 3);
                        CAND(j, rb, dx);
                    }
                }
            } else {
                INSF(__longlong_as_double((long long)((1ull << 62) | 24ull)));
#pragma unroll
                for (int dy = 0; dy <= 3; ++dy) {
                    int rb = (y + dy + 3) * TCOLS + xl + 3;
                    const int dxmin = (dy == 0) ? 1 : -3;
#pragma unroll
                    for (int dx = dxmin; dx <= 3; ++dx) {
                        const int j = (dy + 3) * 7 + (dx + 3);
                        CAND(j, rb, dx);
                    }
                }
                kbuf[pidx][0] = s0; kbuf[pidx][1] = s1; kbuf[pidx][2] = s2;
                kbuf[pidx][3] = s3; kbuf[pidx][4] = s4; kbuf[pidx][5] = s5;
                kbuf[pidx][6] = s6;
            }
            if (role == 0) {
                __syncthreads();
                // Batcher half-cleaner: mins of (a_k, b_{6-k}) = 7 smallest of 14
                double m0 = fmin(s0, kbuf[pidx][6]);
                double m1 = fmin(s1, kbuf[pidx][5]);
                double m2 = fmin(s2, kbuf[pidx][4]);
                double m3 = fmin(s3, kbuf[pidx][3]);
                double m4 = fmin(s4, kbuf[pidx][2]);
                double m5 = fmin(s5, kbuf[pidx][1]);
                double m6 = fmin(s6, kbuf[pidx][0]);

                const double cutmax = __longlong_as_double((long long)CUTOFF_KEYMAX);
                int c0, c1, c2, c3, c4, c5, c6;
                // winner classes gathered from global proj_argmax (L2-hot);
                // zero-pad rows -> class 0; circular in W (R2-proven pattern)
#define CLSK(MK, CK) do {                                                \
                long long kb = __double_as_longlong(MK);                 \
                int j = (int)(kb & 63);                                  \
                bool sel = (MK) <= cutmax;                               \
                int dy7 = (j * 37) >> 8;                                 \
                int sr = y + dy7 - 3;                                    \
                bool vrow = (unsigned)sr < (unsigned)H;                  \
                int src = min(max(sr, 0), H - 1);                        \
                int colw = (tbase - 3 + xl + (j - dy7 * 7)) & (W - 1);   \
                int cc = proj_argmax[src * W + colw];                    \
                CK = (sel && vrow) ? cc : 0;                             \
            } while (0)
                CLSK(m0, c0); CLSK(m1, c1); CLSK(m2, c2); CLSK(m3, c3);
                CLSK(m4, c4); CLSK(m5, c5); CLSK(m6, c6);
#undef CLSK

                int n0 = 1, n1 = 1, n2 = 1, n3 = 1, n4 = 1, n5 = 1, n6 = 1;
#define PAIRV(A, B) do { bool e = (c##A == c##B); n##A += e ? 1 : 0; n##B += e ? 1 : 0; } while (0)
                PAIRV(0,1); PAIRV(0,2); PAIRV(0,3); PAIRV(0,4); PAIRV(0,5); PAIRV(0,6);
                PAIRV(1,2); PAIRV(1,3); PAIRV(1,4); PAIRV(1,5); PAIRV(1,6);
                PAIRV(2,3); PAIRV(2,4); PAIRV(2,5); PAIRV(2,6);
                PAIRV(3,4); PAIRV(3,5); PAIRV(3,6);
                PAIRV(4,5); PAIRV(4,6);
                PAIRV(5,6);
#undef PAIRV

                int best = 0;
#define SCORE(K) do {                                                    \
                bool valid = (unsigned)(c##K - 1) < (unsigned)(NCLASSES - 1);\
                int sc = valid ? ((n##K << 5) | (31 - c##K)) : 0;        \
                best = max(best, sc);                                    \
            } while (0)
                SCORE(0); SCORE(1); SCORE(2); SCORE(3); SCORE(4); SCORE(5); SCORE(6);
#undef SCORE
                if (active) {
                    int res = (best == 0) ? 1 : (31 - (best & 31));
                    __builtin_nontemporal_store(res, &outv[i]);
                }
                __syncthreads();             // matches role-1's barriers below
            } else {
                __syncthreads();
                __syncthreads();
            }
        } else {
            __syncthreads();
            __syncthreads();
        }
    }
}

extern "C" void kernel_launch(void* const* d_in, const int* in_sizes, int n_in,
                              void* d_out, int out_size, void* d_ws, size_t ws_size,
                              hipStream_t stream) {
    const float* proj_range   = (const float*)d_in[0];
    const float* unproj_range = (const float*)d_in[1];
    const int*   proj_argmax  = (const int*)d_in[2];
    const int*   px           = (const int*)d_in[3];
    const int*   py           = (const int*)d_in[4];
    int* out = (int*)d_out;

    // Emulate numpy float32 pipeline for the inverse-gaussian table.
    InvG invg;
    float g[S2];
    for (int yy = 0; yy < SEARCH; ++yy) {
        for (int xx = 0; xx < SEARCH; ++xx) {
            float fdx = (float)xx - 3.0f;
            float fdy = (float)yy - 3.0f;
            float s   = fdx * fdx + fdy * fdy;
            float arg = -s / 2.0f;
            float e   = (float)exp((double)arg);
            float gg  = e / 6.2831855f;
            g[yy * SEARCH + xx] = gg;
        }
    }
    float r[8];
    for (int tt = 0; tt < 8; ++tt) r[tt] = g[tt];
    int ii;
    for (ii = 8; ii + 8 <= 48; ii += 8)
        for (int tt = 0; tt < 8; ++tt) r[tt] += g[ii + tt];
    float ssum = ((r[0] + r[1]) + (r[2] + r[3])) + ((r[4] + r[5]) + (r[6] + r[7]));
    for (; ii < S2; ++ii) ssum += g[ii];
    for (int tt = 0; tt < S2; ++tt) invg.v[tt] = 1.0f - (g[tt] / ssum);

    knn_kernel<<<NTILES * SPT, KBLOCK, 0, stream>>>(
        proj_range, unproj_range, proj_argmax, px, py, out, invg);
}